// Round 4
// baseline (480.915 us; speedup 1.0000x reference)
//
#include <hip/hip_runtime.h>
#include <hip/hip_bf16.h>

#define N_ROWS 4096
#define IN_DIM 768
#define OUT_DIM 512

#define BM 128
#define BN 128
#define BK 64
// LDS tiles: rows x 64 bf16 cols, row stride 64 elems (128 B), XOR-swizzled:
// 16B chunk lc of row r lives at physical chunk lc^(r&7). Measured 0 conflicts (R2+).

using bf16x8 = __attribute__((ext_vector_type(8))) short;
using f32x4  = __attribute__((ext_vector_type(4))) float;

__device__ __constant__ int c_docmap[6] = {0, 1, 0, 2, 1, 2};

__device__ inline unsigned short f2bf(float f) {
    __hip_bfloat16 h = __float2bfloat16(f);
    return reinterpret_cast<unsigned short&>(h);
}
__device__ inline float bf2f(unsigned short u) {
    return __uint_as_float((unsigned int)u << 16);
}

// ---------------- fused prep: doc conversion + weight transposes ----------------
// seg(blockIdx.y): 0..2 = doc d->bf16; 3 = W1 transpose [z][768][512]->[z][512][768];
// 4 = W2 transpose [z][512][512]->[z][512][512]. 4 elems/thread.
__global__ void prep(const float* __restrict__ d0, const float* __restrict__ d1,
                     const float* __restrict__ d2, const float* __restrict__ W1s,
                     const float* __restrict__ W2s, unsigned short* __restrict__ Xb,
                     unsigned short* __restrict__ W1t, unsigned short* __restrict__ W2t) {
    int seg = blockIdx.y;
    size_t i4 = ((size_t)blockIdx.x * 256 + threadIdx.x) * 4;
    if (seg < 3) {
        const size_t n1 = (size_t)N_ROWS * IN_DIM;
        if (i4 >= n1) return;
        const float* src = (seg == 0) ? d0 : ((seg == 1) ? d1 : d2);
        float4 v = *(const float4*)(src + i4);
        ushort4 o;
        o.x = f2bf(v.x); o.y = f2bf(v.y); o.z = f2bf(v.z); o.w = f2bf(v.w);
        *(ushort4*)(Xb + seg * n1 + i4) = o;
    } else if (seg == 3) {
        const size_t tot = (size_t)6 * IN_DIM * OUT_DIM;
        if (i4 >= tot) return;
        size_t r = i4;
        int z = (int)(r / ((size_t)OUT_DIM * IN_DIM)); r %= (size_t)OUT_DIM * IN_DIM;
        int n = (int)(r / IN_DIM);
        int k = (int)(r % IN_DIM);
        const float* W = W1s + (size_t)z * IN_DIM * OUT_DIM;
        ushort4 o;
        o.x = f2bf(W[(size_t)(k + 0) * OUT_DIM + n]);
        o.y = f2bf(W[(size_t)(k + 1) * OUT_DIM + n]);
        o.z = f2bf(W[(size_t)(k + 2) * OUT_DIM + n]);
        o.w = f2bf(W[(size_t)(k + 3) * OUT_DIM + n]);
        *(ushort4*)(W1t + i4) = o;
    } else {
        const size_t tot = (size_t)6 * OUT_DIM * OUT_DIM;
        if (i4 >= tot) return;
        size_t r = i4;
        int z = (int)(r / ((size_t)OUT_DIM * OUT_DIM)); r %= (size_t)OUT_DIM * OUT_DIM;
        int n = (int)(r / OUT_DIM);
        int k = (int)(r % OUT_DIM);
        const float* W = W2s + (size_t)z * OUT_DIM * OUT_DIM;
        ushort4 o;
        o.x = f2bf(W[(size_t)(k + 0) * OUT_DIM + n]);
        o.y = f2bf(W[(size_t)(k + 1) * OUT_DIM + n]);
        o.z = f2bf(W[(size_t)(k + 2) * OUT_DIM + n]);
        o.w = f2bf(W[(size_t)(k + 3) * OUT_DIM + n]);
        *(ushort4*)(W2t + i4) = o;
    }
}

// ---------------- async swizzled staging ----------------

// 4-wave: 128 rows x 64 cols (256-thread GEMMs)
__device__ inline void stage_tile_async(const unsigned short* __restrict__ G, int ld,
                                        int row0, int k0, unsigned short* lds,
                                        int wave, int lane) {
    int rbase = wave * 32;
#pragma unroll
    for (int i = 0; i < 4; ++i) {
        int rs = rbase + i * 8;
        int r  = rs + (lane >> 3);
        int pc = lane & 7;
        int lc = pc ^ (r & 7);
        const unsigned short* g = G + (size_t)(row0 + r) * ld + k0 + lc * 8;
        unsigned short* l = lds + rs * 64;
        __builtin_amdgcn_global_load_lds(
            (const __attribute__((address_space(1))) unsigned int*)g,
            (__attribute__((address_space(3))) unsigned int*)l, 16, 0, 0);
    }
}

// 8-wave: 256 rows x 64 cols
__device__ inline void stageA512(const unsigned short* __restrict__ G, int ld,
                                 int row0, int k0, unsigned short* lds,
                                 int wave, int lane) {
    int rbase = wave * 32;
#pragma unroll
    for (int i = 0; i < 4; ++i) {
        int rs = rbase + i * 8;
        int r  = rs + (lane >> 3);
        int pc = lane & 7;
        int lc = pc ^ (r & 7);
        const unsigned short* g = G + (size_t)(row0 + r) * ld + k0 + lc * 8;
        unsigned short* l = lds + rs * 64;
        __builtin_amdgcn_global_load_lds(
            (const __attribute__((address_space(1))) unsigned int*)g,
            (__attribute__((address_space(3))) unsigned int*)l, 16, 0, 0);
    }
}

// 8-wave: 128 rows x 64 cols
__device__ inline void stageB512(const unsigned short* __restrict__ G, int ld,
                                 int row0, int k0, unsigned short* lds,
                                 int wave, int lane) {
    int rbase = wave * 16;
#pragma unroll
    for (int i = 0; i < 2; ++i) {
        int rs = rbase + i * 8;
        int r  = rs + (lane >> 3);
        int pc = lane & 7;
        int lc = pc ^ (r & 7);
        const unsigned short* g = G + (size_t)(row0 + r) * ld + k0 + lc * 8;
        unsigned short* l = lds + rs * 64;
        __builtin_amdgcn_global_load_lds(
            (const __attribute__((address_space(1))) unsigned int*)g,
            (__attribute__((address_space(3))) unsigned int*)l, 16, 0, 0);
    }
}

__device__ inline void mfma_step_swz(const unsigned short* As, const unsigned short* Bs,
                                     int wrow, int wcol, int lane15, int quad,
                                     f32x4 acc[4][4]) {
#pragma unroll
    for (int kk = 0; kk < BK; kk += 32) {
        int lcb = (kk >> 3) + quad;
        bf16x8 aF[4], bF[4];
#pragma unroll
        for (int t = 0; t < 4; ++t) {
            int row = wrow + t * 16 + lane15;
            aF[t] = *(const bf16x8*)(As + row * 64 + ((lcb ^ (row & 7)) * 8));
        }
#pragma unroll
        for (int t = 0; t < 4; ++t) {
            int row = wcol + t * 16 + lane15;
            bF[t] = *(const bf16x8*)(Bs + row * 64 + ((lcb ^ (row & 7)) * 8));
        }
#pragma unroll
        for (int mt = 0; mt < 4; ++mt)
#pragma unroll
            for (int nt = 0; nt < 4; ++nt)
                acc[mt][nt] = __builtin_amdgcn_mfma_f32_16x16x32_bf16(aF[mt], bF[nt], acc[mt][nt], 0, 0, 0);
    }
}

// ---------------- GEMM1: X @ W1^T + b1, fused BN-stats, bf16 out ----------------

__global__ __launch_bounds__(256) void gemm1_bn(
    const unsigned short* __restrict__ Xb, const unsigned short* __restrict__ W1t,
    const float* __restrict__ biasAll, unsigned short* __restrict__ Hb,
    float* __restrict__ stats) {
    int z = blockIdx.z;
    const unsigned short* A = Xb + (size_t)c_docmap[z] * N_ROWS * IN_DIM;
    const unsigned short* B = W1t + (size_t)z * OUT_DIM * IN_DIM;
    const float* bz = biasAll + (size_t)z * OUT_DIM;
    unsigned short* C = Hb + (size_t)z * N_ROWS * OUT_DIM;

    int m0 = blockIdx.y * BM, n0 = blockIdx.x * BN;
    int tid = threadIdx.x;
    int wave = tid >> 6, lane = tid & 63;
    int lane15 = lane & 15, quad = lane >> 4;
    int wrow = (wave >> 1) * 64, wcol = (wave & 1) * 64;

    __shared__ unsigned short As[BM * 64];
    __shared__ unsigned short Bs[BN * 64];

    f32x4 acc[4][4];
#pragma unroll
    for (int mt = 0; mt < 4; ++mt)
#pragma unroll
        for (int nt = 0; nt < 4; ++nt)
            acc[mt][nt] = (f32x4){0.f, 0.f, 0.f, 0.f};

    for (int k0 = 0; k0 < IN_DIM; k0 += BK) {
        stage_tile_async(A, IN_DIM, m0, k0, As, wave, lane);
        stage_tile_async(B, IN_DIM, n0, k0, Bs, wave, lane);
        __syncthreads();
        mfma_step_swz(As, Bs, wrow, wcol, lane15, quad, acc);
        __syncthreads();
    }

    float s1[4] = {0.f, 0.f, 0.f, 0.f}, s2[4] = {0.f, 0.f, 0.f, 0.f};
#pragma unroll
    for (int nt = 0; nt < 4; ++nt) {
        int col = n0 + wcol + nt * 16 + lane15;
        float bv = bz[col];
#pragma unroll
        for (int mt = 0; mt < 4; ++mt)
#pragma unroll
            for (int r = 0; r < 4; ++r) {
                int row = m0 + wrow + mt * 16 + quad * 4 + r;
                float v = acc[mt][nt][r] + bv;
                C[(size_t)row * OUT_DIM + col] = f2bf(v);
                s1[nt] += v; s2[nt] += v * v;
            }
    }
#pragma unroll
    for (int nt = 0; nt < 4; ++nt) {
        float a = s1[nt], b = s2[nt];
        a += __shfl_xor(a, 16); a += __shfl_xor(a, 32);
        b += __shfl_xor(b, 16); b += __shfl_xor(b, 32);
        if (quad == 0) {
            int col = n0 + wcol + nt * 16 + lane15;
            atomicAdd(&stats[((size_t)z * OUT_DIM + col) * 2 + 0], a);
            atomicAdd(&stats[((size_t)z * OUT_DIM + col) * 2 + 1], b);
        }
    }
}

// ---------------- BN apply + ReLU (in place, bf16) ----------------

__global__ void bn_apply(unsigned short* __restrict__ Hb, const float* __restrict__ stats,
                         const float* __restrict__ gammas, const float* __restrict__ betas) {
    size_t i4 = ((size_t)blockIdx.x * blockDim.x + threadIdx.x) * 4;
    if (i4 >= (size_t)6 * N_ROWS * OUT_DIM) return;
    int c = (int)(i4 % OUT_DIM);
    int k = (int)(i4 / ((size_t)N_ROWS * OUT_DIM));
    ushort4 h = *(ushort4*)(Hb + i4);
    unsigned short hv[4] = {h.x, h.y, h.z, h.w};
    ushort4 o;
    unsigned short* ov = (unsigned short*)&o;
#pragma unroll
    for (int j = 0; j < 4; ++j) {
        size_t sc = (size_t)k * OUT_DIM + c + j;
        float mu = stats[sc * 2 + 0] * (1.f / N_ROWS);
        float var = stats[sc * 2 + 1] * (1.f / N_ROWS) - mu * mu;
        float v = (bf2f(hv[j]) - mu) * rsqrtf(var + 1e-5f) * gammas[sc] + betas[sc];
        ov[j] = f2bf(fmaxf(v, 0.f));
    }
    *(ushort4*)(Hb + i4) = o;
}

// ---------------- GEMM2: H @ W2^T + b2, fused row-sumsq, bf16 out ----------------

__global__ __launch_bounds__(256) void gemm2_norm(
    const unsigned short* __restrict__ Hb, const unsigned short* __restrict__ W2t,
    const float* __restrict__ biasAll, unsigned short* __restrict__ O,
    float* __restrict__ rowsumsq) {
    int z = blockIdx.z;
    const unsigned short* A = Hb + (size_t)z * N_ROWS * OUT_DIM;
    const unsigned short* B = W2t + (size_t)z * OUT_DIM * OUT_DIM;
    const float* bz = biasAll + (size_t)z * OUT_DIM;
    unsigned short* C = O + (size_t)z * N_ROWS * OUT_DIM;
    float* rq = rowsumsq + (size_t)z * N_ROWS;

    int m0 = blockIdx.y * BM, n0 = blockIdx.x * BN;
    int tid = threadIdx.x;
    int wave = tid >> 6, lane = tid & 63;
    int lane15 = lane & 15, quad = lane >> 4;
    int wrow = (wave >> 1) * 64, wcol = (wave & 1) * 64;

    __shared__ unsigned short As[BM * 64];
    __shared__ unsigned short Bs[BN * 64];

    f32x4 acc[4][4];
#pragma unroll
    for (int mt = 0; mt < 4; ++mt)
#pragma unroll
        for (int nt = 0; nt < 4; ++nt)
            acc[mt][nt] = (f32x4){0.f, 0.f, 0.f, 0.f};

    for (int k0 = 0; k0 < OUT_DIM; k0 += BK) {
        stage_tile_async(A, OUT_DIM, m0, k0, As, wave, lane);
        stage_tile_async(B, OUT_DIM, n0, k0, Bs, wave, lane);
        __syncthreads();
        mfma_step_swz(As, Bs, wrow, wcol, lane15, quad, acc);
        __syncthreads();
    }

    float rs[16];
#pragma unroll
    for (int j = 0; j < 16; ++j) rs[j] = 0.f;
#pragma unroll
    for (int nt = 0; nt < 4; ++nt) {
        int col = n0 + wcol + nt * 16 + lane15;
        float bv = bz[col];
#pragma unroll
        for (int mt = 0; mt < 4; ++mt)
#pragma unroll
            for (int r = 0; r < 4; ++r) {
                int row = m0 + wrow + mt * 16 + quad * 4 + r;
                float v = acc[mt][nt][r] + bv;
                C[(size_t)row * OUT_DIM + col] = f2bf(v);
                rs[mt * 4 + r] += v * v;
            }
    }
#pragma unroll
    for (int j = 0; j < 16; ++j) {
        float v = rs[j];
        v += __shfl_xor(v, 1); v += __shfl_xor(v, 2);
        v += __shfl_xor(v, 4); v += __shfl_xor(v, 8);
        if (lane15 == 0) {
            int row = m0 + wrow + (j >> 2) * 16 + quad * 4 + (j & 3);
            atomicAdd(&rq[row], v);
        }
    }
}

// ---------------- row L2 norm (bf16 in/out, precomputed sumsq) ----------------

__global__ __launch_bounds__(256) void l2norm(const unsigned short* __restrict__ O,
                                              const float* __restrict__ rowsumsq,
                                              unsigned short* __restrict__ A) {
    int wave = threadIdx.x >> 6, lane = threadIdx.x & 63;
    int row = blockIdx.x * 4 + wave;
    float ss = rowsumsq[row];
    float sc = 1.f / fmaxf(sqrtf(ss), 1e-12f);
    const unsigned short* Op = O + (size_t)row * OUT_DIM + lane * 8;
    uint4 u = *(const uint4*)Op;
    unsigned int w[4] = {u.x, u.y, u.z, u.w};
    ushort4 o0, o1;
    unsigned short* ov = (unsigned short*)&o0;
#pragma unroll
    for (int j = 0; j < 8; ++j) {
        unsigned short us = (j & 1) ? (unsigned short)(w[j >> 1] >> 16)
                                    : (unsigned short)(w[j >> 1] & 0xffff);
        ov[j] = f2bf(bf2f(us) * sc);
    }
    unsigned short* Ap = A + (size_t)row * OUT_DIM + lane * 8;
    *(ushort4*)(Ap) = o0;
    *(ushort4*)(Ap + 4) = o1;
}

// ---------------- symmetric Gram, 256x128 tiles, single-buffer, 2 blocks/CU ----------------

// Per pair p: Cm = [o1;o2] is [8192][512] bf16, L2-normalized rows.
// Row-tiles I of 256 (32 of them), col-tiles J of 128 (64), J >= 2I: 1056 blocks/pair.
// Uniform element masking: grow<gcol -> exp to rowsum[grow] AND rowsum[gcol];
// grow==gcol -> selfdot; grow>gcol -> skip (mirror handled elsewhere in band tiles).
__global__ __launch_bounds__(512, 4) void gram_kernel(const unsigned short* __restrict__ Abase,
                                                      float* __restrict__ rowsum,
                                                      float* __restrict__ selfdot,
                                                      float* __restrict__ crossdot) {
    int p = blockIdx.z;
    const unsigned short* Cm = Abase + (size_t)p * 2 * N_ROWS * OUT_DIM;

    int idx = blockIdx.x, I = 0;
    while (idx >= 64 - 2 * I) { idx -= 64 - 2 * I; ++I; }
    int J = 2 * I + idx;
    int m0 = I * 256, n0 = J * 128;

    int tid = threadIdx.x;
    int wave = tid >> 6, lane = tid & 63;
    int lane15 = lane & 15, quad = lane >> 4;
    int wrow = (wave >> 1) * 64, wcol = (wave & 1) * 64;

    __shared__ unsigned short As[256 * 64];   // 32 KB
    __shared__ unsigned short Bs[128 * 64];   // 16 KB

    f32x4 acc[4][4];
#pragma unroll
    for (int mt = 0; mt < 4; ++mt)
#pragma unroll
        for (int nt = 0; nt < 4; ++nt)
            acc[mt][nt] = (f32x4){0.f, 0.f, 0.f, 0.f};

    for (int k0 = 0; k0 < OUT_DIM; k0 += BK) {
        stageA512(Cm, OUT_DIM, m0, k0, As, wave, lane);
        stageB512(Cm, OUT_DIM, n0, k0, Bs, wave, lane);
        __syncthreads();
        mfma_step_swz(As, Bs, wrow, wcol, lane15, quad, acc);
        __syncthreads();
    }

    float* sdp = selfdot + (size_t)p * 2 * N_ROWS;
    float* cdp = crossdot + (size_t)p * 2 * N_ROWS;
    float* rp  = rowsum  + (size_t)p * 2 * N_ROWS;

    float rs[16];
    float cs[4];
#pragma unroll
    for (int j = 0; j < 16; ++j) rs[j] = 0.f;
#pragma unroll
    for (int j = 0; j < 4; ++j) cs[j] = 0.f;

#pragma unroll
    for (int mt = 0; mt < 4; ++mt)
#pragma unroll
        for (int nt = 0; nt < 4; ++nt) {
            int gcol = n0 + wcol + nt * 16 + lane15;
#pragma unroll
            for (int r = 0; r < 4; ++r) {
                int grow = m0 + wrow + mt * 16 + quad * 4 + r;
                float s = acc[mt][nt][r];
                if (grow < gcol) {
                    float e = __expf(2.f * s);
                    rs[mt * 4 + r] += e;
                    cs[nt] += e;
                }
                if (grow == gcol) sdp[grow] = s;
                if (gcol == grow + N_ROWS) { cdp[grow] = s; cdp[gcol] = s; }
            }
        }

#pragma unroll
    for (int j = 0; j < 16; ++j) {
        float v = rs[j];
        v += __shfl_xor(v, 1); v += __shfl_xor(v, 2);
        v += __shfl_xor(v, 4); v += __shfl_xor(v, 8);
        rs[j] = v;
    }
    if (lane15 == 0) {
#pragma unroll
        for (int j = 0; j < 16; ++j) {
            int grow = m0 + wrow + (j >> 2) * 16 + quad * 4 + (j & 3);
            atomicAdd(&rp[grow], rs[j]);
        }
    }

#pragma unroll
    for (int n = 0; n < 4; ++n) {
        float v = cs[n];
        v += __shfl_xor(v, 16); v += __shfl_xor(v, 32);
        cs[n] = v;
    }
    if (quad == 0) {
#pragma unroll
        for (int n = 0; n < 4; ++n) {
            int gcol = n0 + wcol + n * 16 + lane15;
            atomicAdd(&rp[gcol], cs[n]);
        }
    }
}

// ---------------- final loss reduction ----------------

__global__ void loss_kernel(const float* __restrict__ rowsum, const float* __restrict__ selfdot,
                            const float* __restrict__ crossdot, float* __restrict__ out) {
    __shared__ float red[256];
    float acc = 0.f;
    for (int i = threadIdx.x; i < 3 * 2 * N_ROWS; i += 256) {
        // selfdot excluded from rowsum at accumulation time (grow==gcol skipped)
        float denom = rowsum[i];
        acc += logf(denom) - 2.f * crossdot[i];
    }
    red[threadIdx.x] = acc;
    __syncthreads();
    for (int s = 128; s > 0; s >>= 1) {
        if (threadIdx.x < s) red[threadIdx.x] += red[threadIdx.x + s];
        __syncthreads();
    }
    if (threadIdx.x == 0) out[0] = red[0] * (1.f / 24576.f);
}

// ---------------- launch ----------------

extern "C" void kernel_launch(void* const* d_in, const int* in_sizes, int n_in,
                              void* d_out, int out_size, void* d_ws, size_t ws_size,
                              hipStream_t stream) {
    const float* doc0   = (const float*)d_in[0];
    const float* doc1   = (const float*)d_in[1];
    const float* doc2   = (const float*)d_in[2];
    const float* W1s    = (const float*)d_in[3];
    const float* b1s    = (const float*)d_in[4];
    const float* gammas = (const float*)d_in[5];
    const float* betas  = (const float*)d_in[6];
    const float* W2s    = (const float*)d_in[7];
    const float* b2s    = (const float*)d_in[8];
    float* out = (float*)d_out;

    char* base = (char*)d_ws;
    size_t off = 0;
    auto alloc = [&](size_t bytes) -> char* {
        char* r = base + off;
        off += (bytes + 255) & ~(size_t)255;
        return r;
    };

    unsigned short* Xb   = (unsigned short*)alloc((size_t)3 * N_ROWS * IN_DIM * 2);
    unsigned short* W1t  = (unsigned short*)alloc((size_t)6 * OUT_DIM * IN_DIM * 2);
    unsigned short* W2t  = (unsigned short*)alloc((size_t)6 * OUT_DIM * OUT_DIM * 2);
    unsigned short* Hb   = (unsigned short*)alloc((size_t)6 * N_ROWS * OUT_DIM * 2);
    unsigned short* O    = (unsigned short*)alloc((size_t)6 * N_ROWS * OUT_DIM * 2);
    unsigned short* Abuf = (unsigned short*)alloc((size_t)6 * N_ROWS * OUT_DIM * 2);
    // zero-init region (contiguous, one memset): stats 24576 B + rowsumsq 98304 B + rowsum 98304 B
    char* zbase = alloc(24576 + 98304 + 98304);
    float* stats    = (float*)zbase;
    float* rowsumsq = (float*)(zbase + 24576);
    float* rowsum   = (float*)(zbase + 24576 + 98304);
    float* sdot     = (float*)alloc((size_t)3 * 2 * N_ROWS * 4);
    float* cdot     = (float*)alloc((size_t)3 * 2 * N_ROWS * 4);

    if (ws_size < off) return;

    hipMemsetAsync(zbase, 0, 24576 + 98304 + 98304, stream);

    // fused conversions: docs + W1/W2 transposes
    prep<<<dim3(3072, 5), 256, 0, stream>>>(doc0, doc1, doc2, W1s, W2s, Xb, W1t, W2t);

    gemm1_bn<<<dim3(OUT_DIM / BN, N_ROWS / BM, 6), 256, 0, stream>>>(Xb, W1t, b1s, Hb, stats);

    bn_apply<<<(int)(((size_t)6 * N_ROWS * OUT_DIM / 4 + 255) / 256), 256, 0, stream>>>(
        Hb, stats, gammas, betas);

    gemm2_norm<<<dim3(OUT_DIM / BN, N_ROWS / BM, 6), 256, 0, stream>>>(Hb, W2t, b2s, O, rowsumsq);

    l2norm<<<6 * N_ROWS / 4, 256, 0, stream>>>(O, rowsumsq, Abuf);

    // symmetric gram: 256-row x 128-col tiles, J>=2I: 1056 blocks per pair
    gram_kernel<<<dim3(1056, 1, 3), 512, 0, stream>>>(Abuf, rowsum, sdot, cdot);

    loss_kernel<<<1, 256, 0, stream>>>(rowsum, sdot, cdot, out);
}

// Round 5
// 399.434 us; speedup vs baseline: 1.2040x; 1.2040x over previous
//
#include <hip/hip_runtime.h>
#include <hip/hip_bf16.h>
#include <hip/hip_fp8.h>

#define N_ROWS 4096
#define IN_DIM 768
#define OUT_DIM 512

#define BM 128
#define BN 128
#define BK 64
// bf16 LDS tiles: rows x 64 cols, row stride 128 B, XOR-swizzled 16B chunks:
// chunk lc of row r at physical chunk lc^(r&7). Measured 0 conflicts (R2+).
// fp8 gram tiles: rows x 128 cols (128 B rows), same 8-chunk swizzle.

using bf16x8 = __attribute__((ext_vector_type(8))) short;
using f32x4  = __attribute__((ext_vector_type(4))) float;
using i64    = long;

__device__ __constant__ int c_docmap[6] = {0, 1, 0, 2, 1, 2};

__device__ inline unsigned short f2bf(float f) {
    __hip_bfloat16 h = __float2bfloat16(f);
    return reinterpret_cast<unsigned short&>(h);
}
__device__ inline float bf2f(unsigned short u) {
    return __uint_as_float((unsigned int)u << 16);
}
__device__ inline unsigned char f2fp8(float f) {
    __hip_fp8_e4m3 t(f);           // OCP e4m3fn, RNE+sat
    return t.__x;
}

// ---------------- fused prep: doc conversion + weight transposes ----------------
__global__ void prep(const float* __restrict__ d0, const float* __restrict__ d1,
                     const float* __restrict__ d2, const float* __restrict__ W1s,
                     const float* __restrict__ W2s, unsigned short* __restrict__ Xb,
                     unsigned short* __restrict__ W1t, unsigned short* __restrict__ W2t) {
    int seg = blockIdx.y;
    size_t i4 = ((size_t)blockIdx.x * 256 + threadIdx.x) * 4;
    if (seg < 3) {
        const size_t n1 = (size_t)N_ROWS * IN_DIM;
        if (i4 >= n1) return;
        const float* src = (seg == 0) ? d0 : ((seg == 1) ? d1 : d2);
        float4 v = *(const float4*)(src + i4);
        ushort4 o;
        o.x = f2bf(v.x); o.y = f2bf(v.y); o.z = f2bf(v.z); o.w = f2bf(v.w);
        *(ushort4*)(Xb + seg * n1 + i4) = o;
    } else if (seg == 3) {
        const size_t tot = (size_t)6 * IN_DIM * OUT_DIM;
        if (i4 >= tot) return;
        size_t r = i4;
        int z = (int)(r / ((size_t)OUT_DIM * IN_DIM)); r %= (size_t)OUT_DIM * IN_DIM;
        int n = (int)(r / IN_DIM);
        int k = (int)(r % IN_DIM);
        const float* W = W1s + (size_t)z * IN_DIM * OUT_DIM;
        ushort4 o;
        o.x = f2bf(W[(size_t)(k + 0) * OUT_DIM + n]);
        o.y = f2bf(W[(size_t)(k + 1) * OUT_DIM + n]);
        o.z = f2bf(W[(size_t)(k + 2) * OUT_DIM + n]);
        o.w = f2bf(W[(size_t)(k + 3) * OUT_DIM + n]);
        *(ushort4*)(W1t + i4) = o;
    } else {
        const size_t tot = (size_t)6 * OUT_DIM * OUT_DIM;
        if (i4 >= tot) return;
        size_t r = i4;
        int z = (int)(r / ((size_t)OUT_DIM * OUT_DIM)); r %= (size_t)OUT_DIM * OUT_DIM;
        int n = (int)(r / OUT_DIM);
        int k = (int)(r % OUT_DIM);
        const float* W = W2s + (size_t)z * OUT_DIM * OUT_DIM;
        ushort4 o;
        o.x = f2bf(W[(size_t)(k + 0) * OUT_DIM + n]);
        o.y = f2bf(W[(size_t)(k + 1) * OUT_DIM + n]);
        o.z = f2bf(W[(size_t)(k + 2) * OUT_DIM + n]);
        o.w = f2bf(W[(size_t)(k + 3) * OUT_DIM + n]);
        *(ushort4*)(W2t + i4) = o;
    }
}

// ---------------- async swizzled staging (bf16, 128 rows x 64 cols) ----------------
__device__ inline void stage_tile_async(const unsigned short* __restrict__ G, int ld,
                                        int row0, int k0, unsigned short* lds,
                                        int wave, int lane) {
    int rbase = wave * 32;
#pragma unroll
    for (int i = 0; i < 4; ++i) {
        int rs = rbase + i * 8;
        int r  = rs + (lane >> 3);
        int pc = lane & 7;
        int lc = pc ^ (r & 7);
        const unsigned short* g = G + (size_t)(row0 + r) * ld + k0 + lc * 8;
        unsigned short* l = lds + rs * 64;
        __builtin_amdgcn_global_load_lds(
            (const __attribute__((address_space(1))) unsigned int*)g,
            (__attribute__((address_space(3))) unsigned int*)l, 16, 0, 0);
    }
}

__device__ inline void mfma_step_swz(const unsigned short* As, const unsigned short* Bs,
                                     int wrow, int wcol, int lane15, int quad,
                                     f32x4 acc[4][4]) {
#pragma unroll
    for (int kk = 0; kk < BK; kk += 32) {
        int lcb = (kk >> 3) + quad;
        bf16x8 aF[4], bF[4];
#pragma unroll
        for (int t = 0; t < 4; ++t) {
            int row = wrow + t * 16 + lane15;
            aF[t] = *(const bf16x8*)(As + row * 64 + ((lcb ^ (row & 7)) * 8));
        }
#pragma unroll
        for (int t = 0; t < 4; ++t) {
            int row = wcol + t * 16 + lane15;
            bF[t] = *(const bf16x8*)(Bs + row * 64 + ((lcb ^ (row & 7)) * 8));
        }
#pragma unroll
        for (int mt = 0; mt < 4; ++mt)
#pragma unroll
            for (int nt = 0; nt < 4; ++nt)
                acc[mt][nt] = __builtin_amdgcn_mfma_f32_16x16x32_bf16(aF[mt], bF[nt], acc[mt][nt], 0, 0, 0);
    }
}

// ---------------- GEMM1: X @ W1^T + b1, fused BN-stats, FP32 out ----------------
__global__ __launch_bounds__(256) void gemm1_bn(
    const unsigned short* __restrict__ Xb, const unsigned short* __restrict__ W1t,
    const float* __restrict__ biasAll, float* __restrict__ H,
    float* __restrict__ stats) {
    int z = blockIdx.z;
    const unsigned short* A = Xb + (size_t)c_docmap[z] * N_ROWS * IN_DIM;
    const unsigned short* B = W1t + (size_t)z * OUT_DIM * IN_DIM;
    const float* bz = biasAll + (size_t)z * OUT_DIM;
    float* C = H + (size_t)z * N_ROWS * OUT_DIM;

    int m0 = blockIdx.y * BM, n0 = blockIdx.x * BN;
    int tid = threadIdx.x;
    int wave = tid >> 6, lane = tid & 63;
    int lane15 = lane & 15, quad = lane >> 4;
    int wrow = (wave >> 1) * 64, wcol = (wave & 1) * 64;

    __shared__ unsigned short As[BM * 64];
    __shared__ unsigned short Bs[BN * 64];

    f32x4 acc[4][4];
#pragma unroll
    for (int mt = 0; mt < 4; ++mt)
#pragma unroll
        for (int nt = 0; nt < 4; ++nt)
            acc[mt][nt] = (f32x4){0.f, 0.f, 0.f, 0.f};

    for (int k0 = 0; k0 < IN_DIM; k0 += BK) {
        stage_tile_async(A, IN_DIM, m0, k0, As, wave, lane);
        stage_tile_async(B, IN_DIM, n0, k0, Bs, wave, lane);
        __syncthreads();
        mfma_step_swz(As, Bs, wrow, wcol, lane15, quad, acc);
        __syncthreads();
    }

    float s1[4] = {0.f, 0.f, 0.f, 0.f}, s2[4] = {0.f, 0.f, 0.f, 0.f};
#pragma unroll
    for (int nt = 0; nt < 4; ++nt) {
        int col = n0 + wcol + nt * 16 + lane15;
        float bv = bz[col];
#pragma unroll
        for (int mt = 0; mt < 4; ++mt)
#pragma unroll
            for (int r = 0; r < 4; ++r) {
                int row = m0 + wrow + mt * 16 + quad * 4 + r;
                float v = acc[mt][nt][r] + bv;
                C[(size_t)row * OUT_DIM + col] = v;
                s1[nt] += v; s2[nt] += v * v;
            }
    }
#pragma unroll
    for (int nt = 0; nt < 4; ++nt) {
        float a = s1[nt], b = s2[nt];
        a += __shfl_xor(a, 16); a += __shfl_xor(a, 32);
        b += __shfl_xor(b, 16); b += __shfl_xor(b, 32);
        if (quad == 0) {
            int col = n0 + wcol + nt * 16 + lane15;
            atomicAdd(&stats[((size_t)z * OUT_DIM + col) * 2 + 0], a);
            atomicAdd(&stats[((size_t)z * OUT_DIM + col) * 2 + 1], b);
        }
    }
}

// ---------------- BN apply + ReLU: fp32 H -> bf16 Hb ----------------
__global__ void bn_apply(const float* __restrict__ H, unsigned short* __restrict__ Hb,
                         const float* __restrict__ stats, const float* __restrict__ gammas,
                         const float* __restrict__ betas) {
    size_t i4 = ((size_t)blockIdx.x * blockDim.x + threadIdx.x) * 4;
    if (i4 >= (size_t)6 * N_ROWS * OUT_DIM) return;
    int c = (int)(i4 % OUT_DIM);
    int k = (int)(i4 / ((size_t)N_ROWS * OUT_DIM));
    float4 h = *(const float4*)(H + i4);
    float hv[4] = {h.x, h.y, h.z, h.w};
    ushort4 o;
    unsigned short* ov = (unsigned short*)&o;
#pragma unroll
    for (int j = 0; j < 4; ++j) {
        size_t sc = (size_t)k * OUT_DIM + c + j;
        float mu = stats[sc * 2 + 0] * (1.f / N_ROWS);
        float var = stats[sc * 2 + 1] * (1.f / N_ROWS) - mu * mu;
        float v = (hv[j] - mu) * rsqrtf(var + 1e-5f) * gammas[sc] + betas[sc];
        ov[j] = f2bf(fmaxf(v, 0.f));
    }
    *(ushort4*)(Hb + i4) = o;
}

// ---------------- GEMM2: Hb @ W2^T + b2, fused row-sumsq, FP32 out ----------------
__global__ __launch_bounds__(256) void gemm2_norm(
    const unsigned short* __restrict__ Hb, const unsigned short* __restrict__ W2t,
    const float* __restrict__ biasAll, float* __restrict__ O,
    float* __restrict__ rowsumsq) {
    int z = blockIdx.z;
    const unsigned short* A = Hb + (size_t)z * N_ROWS * OUT_DIM;
    const unsigned short* B = W2t + (size_t)z * OUT_DIM * OUT_DIM;
    const float* bz = biasAll + (size_t)z * OUT_DIM;
    float* C = O + (size_t)z * N_ROWS * OUT_DIM;
    float* rq = rowsumsq + (size_t)z * N_ROWS;

    int m0 = blockIdx.y * BM, n0 = blockIdx.x * BN;
    int tid = threadIdx.x;
    int wave = tid >> 6, lane = tid & 63;
    int lane15 = lane & 15, quad = lane >> 4;
    int wrow = (wave >> 1) * 64, wcol = (wave & 1) * 64;

    __shared__ unsigned short As[BM * 64];
    __shared__ unsigned short Bs[BN * 64];

    f32x4 acc[4][4];
#pragma unroll
    for (int mt = 0; mt < 4; ++mt)
#pragma unroll
        for (int nt = 0; nt < 4; ++nt)
            acc[mt][nt] = (f32x4){0.f, 0.f, 0.f, 0.f};

    for (int k0 = 0; k0 < OUT_DIM; k0 += BK) {
        stage_tile_async(A, OUT_DIM, m0, k0, As, wave, lane);
        stage_tile_async(B, OUT_DIM, n0, k0, Bs, wave, lane);
        __syncthreads();
        mfma_step_swz(As, Bs, wrow, wcol, lane15, quad, acc);
        __syncthreads();
    }

    float rs[16];
#pragma unroll
    for (int j = 0; j < 16; ++j) rs[j] = 0.f;
#pragma unroll
    for (int nt = 0; nt < 4; ++nt) {
        int col = n0 + wcol + nt * 16 + lane15;
        float bv = bz[col];
#pragma unroll
        for (int mt = 0; mt < 4; ++mt)
#pragma unroll
            for (int r = 0; r < 4; ++r) {
                int row = m0 + wrow + mt * 16 + quad * 4 + r;
                float v = acc[mt][nt][r] + bv;
                C[(size_t)row * OUT_DIM + col] = v;
                rs[mt * 4 + r] += v * v;
            }
    }
#pragma unroll
    for (int j = 0; j < 16; ++j) {
        float v = rs[j];
        v += __shfl_xor(v, 1); v += __shfl_xor(v, 2);
        v += __shfl_xor(v, 4); v += __shfl_xor(v, 8);
        if (lane15 == 0) {
            int row = m0 + wrow + (j >> 2) * 16 + quad * 4 + (j & 3);
            atomicAdd(&rq[row], v);
        }
    }
}

// ---------------- row L2 norm: fp32 O -> fp8 e4m3 Abuf ----------------
__global__ __launch_bounds__(256) void l2norm_fp8(const float* __restrict__ O,
                                                  const float* __restrict__ rowsumsq,
                                                  unsigned char* __restrict__ A) {
    int wave = threadIdx.x >> 6, lane = threadIdx.x & 63;
    int row = blockIdx.x * 4 + wave;
    float sc = 1.f / fmaxf(sqrtf(rowsumsq[row]), 1e-12f);
    const float* Op = O + (size_t)row * OUT_DIM + lane * 8;
    float4 v0 = *(const float4*)(Op);
    float4 v1 = *(const float4*)(Op + 4);
    float v[8] = {v0.x, v0.y, v0.z, v0.w, v1.x, v1.y, v1.z, v1.w};
    unsigned long long pk = 0;
#pragma unroll
    for (int j = 0; j < 8; ++j)
        pk |= (unsigned long long)f2fp8(v[j] * sc) << (8 * j);
    *(unsigned long long*)(A + (size_t)row * OUT_DIM + lane * 8) = pk;
}

// ---------------- fp8 staging: 128 rows x 128 byte-cols, swizzled ----------------
__device__ inline void stage_fp8(const unsigned char* __restrict__ G, int ld,
                                 int row0, int k0, unsigned char* lds,
                                 int wave, int lane) {
    int rbase = wave * 32;
#pragma unroll
    for (int i = 0; i < 4; ++i) {
        int rs = rbase + i * 8;
        int r  = rs + (lane >> 3);
        int pc = lane & 7;
        int lc = pc ^ (r & 7);
        const unsigned char* g = G + (size_t)(row0 + r) * ld + k0 + lc * 16;
        unsigned char* l = lds + rs * 128;
        __builtin_amdgcn_global_load_lds(
            (const __attribute__((address_space(1))) unsigned int*)g,
            (__attribute__((address_space(3))) unsigned int*)l, 16, 0, 0);
    }
}

// ---------------- symmetric fp8 Gram + exp + row/col-sum ----------------
// Cm = [o1;o2]: [8192][512] fp8 e4m3, rows L2-normalized. Tiles 128x128 over
// 64 row-tiles, I<=J: 2080 blocks/pair. BK=128 bytes -> only 4 barrier pairs.
// MFMA 16x16x32 fp8: A/B = i64 (8 fp8/lane), frag k = quad*8+j within kk-chunk.
__global__ __launch_bounds__(256) void gram_kernel(const unsigned char* __restrict__ Abase,
                                                   float* __restrict__ rowsum,
                                                   float* __restrict__ selfdot,
                                                   float* __restrict__ crossdot) {
    int p = blockIdx.z;
    const unsigned char* Cm = Abase + (size_t)p * 2 * N_ROWS * OUT_DIM;

    int idx = blockIdx.x, I = 0;
    while (idx >= 64 - I) { idx -= 64 - I; ++I; }
    int J = I + idx;
    int m0 = I * BM, n0 = J * BM;
    bool isDiag  = (I == J);
    bool isCross = (J == I + N_ROWS / BM);

    int tid = threadIdx.x;
    int wave = tid >> 6, lane = tid & 63;
    int lane15 = lane & 15, quad = lane >> 4;
    int wrow = (wave >> 1) * 64, wcol = (wave & 1) * 64;

    __shared__ unsigned char As[BM * 128];   // 16 KB
    __shared__ unsigned char Bs[BM * 128];   // 16 KB

    f32x4 acc[4][4];
#pragma unroll
    for (int mt = 0; mt < 4; ++mt)
#pragma unroll
        for (int nt = 0; nt < 4; ++nt)
            acc[mt][nt] = (f32x4){0.f, 0.f, 0.f, 0.f};

    for (int k0 = 0; k0 < OUT_DIM; k0 += 128) {
        stage_fp8(Cm, OUT_DIM, m0, k0, As, wave, lane);
        if (!isDiag) stage_fp8(Cm, OUT_DIM, n0, k0, Bs, wave, lane);
        __syncthreads();
        const unsigned char* Bp = isDiag ? As : Bs;
#pragma unroll
        for (int kk = 0; kk < 128; kk += 32) {
            int cb  = (kk >> 4) + (quad >> 1);   // logical 16B chunk
            int sub = (quad & 1) * 8;            // byte offset within chunk
            i64 aF[4], bF[4];
#pragma unroll
            for (int t = 0; t < 4; ++t) {
                int row = wrow + t * 16 + lane15;
                aF[t] = *(const i64*)(As + row * 128 + ((cb ^ (row & 7)) << 4) + sub);
            }
#pragma unroll
            for (int t = 0; t < 4; ++t) {
                int row = wcol + t * 16 + lane15;
                bF[t] = *(const i64*)(Bp + row * 128 + ((cb ^ (row & 7)) << 4) + sub);
            }
#pragma unroll
            for (int mt = 0; mt < 4; ++mt)
#pragma unroll
                for (int nt = 0; nt < 4; ++nt)
                    acc[mt][nt] = __builtin_amdgcn_mfma_f32_16x16x32_fp8_fp8(
                        aF[mt], bF[nt], acc[mt][nt], 0, 0, 0);
        }
        __syncthreads();
    }

    float* sdp = selfdot + (size_t)p * 2 * N_ROWS;
    float* cdp = crossdot + (size_t)p * 2 * N_ROWS;
    float* rp  = rowsum  + (size_t)p * 2 * N_ROWS;

    float rs[16];
    float cs[4];
#pragma unroll
    for (int j = 0; j < 16; ++j) rs[j] = 0.f;
#pragma unroll
    for (int j = 0; j < 4; ++j) cs[j] = 0.f;

#pragma unroll
    for (int mt = 0; mt < 4; ++mt)
#pragma unroll
        for (int nt = 0; nt < 4; ++nt) {
            int gcol = n0 + wcol + nt * 16 + lane15;
#pragma unroll
            for (int r = 0; r < 4; ++r) {
                int grow = m0 + wrow + mt * 16 + quad * 4 + r;
                float s = acc[mt][nt][r];
                float e = __expf(2.f * s);
                rs[mt * 4 + r] += e;
                cs[nt] += e;
                if (isDiag && gcol == grow) sdp[grow] = s;
                if (isCross && gcol == grow + N_ROWS) { cdp[grow] = s; cdp[gcol] = s; }
            }
        }

#pragma unroll
    for (int j = 0; j < 16; ++j) {
        float v = rs[j];
        v += __shfl_xor(v, 1); v += __shfl_xor(v, 2);
        v += __shfl_xor(v, 4); v += __shfl_xor(v, 8);
        rs[j] = v;
    }
    if (lane15 == 0) {
#pragma unroll
        for (int j = 0; j < 16; ++j) {
            int grow = m0 + wrow + (j >> 2) * 16 + quad * 4 + (j & 3);
            atomicAdd(&rp[grow], rs[j]);
        }
    }

    if (!isDiag) {
#pragma unroll
        for (int n = 0; n < 4; ++n) {
            float v = cs[n];
            v += __shfl_xor(v, 16); v += __shfl_xor(v, 32);
            cs[n] = v;
        }
        if (quad == 0) {
#pragma unroll
            for (int n = 0; n < 4; ++n) {
                int gcol = n0 + wcol + n * 16 + lane15;
                atomicAdd(&rp[gcol], cs[n]);
            }
        }
    }
}

// ---------------- final loss reduction ----------------
__global__ void loss_kernel(const float* __restrict__ rowsum, const float* __restrict__ selfdot,
                            const float* __restrict__ crossdot, float* __restrict__ out) {
    __shared__ float red[256];
    float acc = 0.f;
    for (int i = threadIdx.x; i < 3 * 2 * N_ROWS; i += 256) {
        float denom = rowsum[i] - __expf(2.f * selfdot[i]);
        acc += logf(denom) - 2.f * crossdot[i];
    }
    red[threadIdx.x] = acc;
    __syncthreads();
    for (int s = 128; s > 0; s >>= 1) {
        if (threadIdx.x < s) red[threadIdx.x] += red[threadIdx.x + s];
        __syncthreads();
    }
    if (threadIdx.x == 0) out[0] = red[0] * (1.f / 24576.f);
}

// ---------------- launch ----------------
extern "C" void kernel_launch(void* const* d_in, const int* in_sizes, int n_in,
                              void* d_out, int out_size, void* d_ws, size_t ws_size,
                              hipStream_t stream) {
    const float* doc0   = (const float*)d_in[0];
    const float* doc1   = (const float*)d_in[1];
    const float* doc2   = (const float*)d_in[2];
    const float* W1s    = (const float*)d_in[3];
    const float* b1s    = (const float*)d_in[4];
    const float* gammas = (const float*)d_in[5];
    const float* betas  = (const float*)d_in[6];
    const float* W2s    = (const float*)d_in[7];
    const float* b2s    = (const float*)d_in[8];
    float* out = (float*)d_out;

    char* base = (char*)d_ws;
    size_t off = 0;
    auto alloc = [&](size_t bytes) -> char* {
        char* r = base + off;
        off += (bytes + 255) & ~(size_t)255;
        return r;
    };

    unsigned short* Xb   = (unsigned short*)alloc((size_t)3 * N_ROWS * IN_DIM * 2);
    unsigned short* W1t  = (unsigned short*)alloc((size_t)6 * OUT_DIM * IN_DIM * 2);
    unsigned short* W2t  = (unsigned short*)alloc((size_t)6 * OUT_DIM * OUT_DIM * 2);
    float*          H    = (float*)         alloc((size_t)6 * N_ROWS * OUT_DIM * 4);
    unsigned short* Hb   = (unsigned short*)alloc((size_t)6 * N_ROWS * OUT_DIM * 2);
    float*          O    = (float*)         alloc((size_t)6 * N_ROWS * OUT_DIM * 4);
    unsigned char*  Abuf = (unsigned char*) alloc((size_t)6 * N_ROWS * OUT_DIM);
    // zero-init region (one memset): stats + rowsumsq + rowsum
    char* zbase = alloc(24576 + 98304 + 98304);
    float* stats    = (float*)zbase;
    float* rowsumsq = (float*)(zbase + 24576);
    float* rowsum   = (float*)(zbase + 24576 + 98304);
    float* sdot     = (float*)alloc((size_t)3 * 2 * N_ROWS * 4);
    float* cdot     = (float*)alloc((size_t)3 * 2 * N_ROWS * 4);

    if (ws_size < off) return;

    hipMemsetAsync(zbase, 0, 24576 + 98304 + 98304, stream);

    prep<<<dim3(3072, 5), 256, 0, stream>>>(doc0, doc1, doc2, W1s, W2s, Xb, W1t, W2t);

    gemm1_bn<<<dim3(OUT_DIM / BN, N_ROWS / BM, 6), 256, 0, stream>>>(Xb, W1t, b1s, H, stats);

    bn_apply<<<(int)(((size_t)6 * N_ROWS * OUT_DIM / 4 + 255) / 256), 256, 0, stream>>>(
        H, Hb, stats, gammas, betas);

    gemm2_norm<<<dim3(OUT_DIM / BN, N_ROWS / BM, 6), 256, 0, stream>>>(Hb, W2t, b2s, O, rowsumsq);

    l2norm_fp8<<<6 * N_ROWS / 4, 256, 0, stream>>>(O, rowsumsq, Abuf);

    // symmetric fp8 gram: 64*65/2 = 2080 tile-pairs per pair, 3 pairs
    gram_kernel<<<dim3(2080, 1, 3), 256, 0, stream>>>(Abuf, rowsum, sdot, cdot);

    loss_kernel<<<1, 256, 0, stream>>>(rowsum, sdot, cdot, out);
}

// Round 6
// 386.021 us; speedup vs baseline: 1.2458x; 1.0347x over previous
//
#include <hip/hip_runtime.h>
#include <hip/hip_bf16.h>
#include <hip/hip_fp8.h>

#define N_ROWS 4096
#define IN_DIM 768
#define OUT_DIM 512

#define BM 128
#define BN 128
#define BK 64
// bf16 LDS tiles: rows x 64 cols (128 B rows), XOR-swizzled 16B chunks:
// chunk lc of row r at physical chunk lc^(r&7). 0 conflicts measured (R2+).
// fp8 gram: K-PERMUTED layout (see l2norm_fp8) so each lane's 2 consecutive
// kk-fragments are 16B contiguous -> ds_read_b128, bank-balanced (8x32 banks).

using bf16x8 = __attribute__((ext_vector_type(8))) short;
using f32x4  = __attribute__((ext_vector_type(4))) float;
using i64    = long;
using i64x2  = __attribute__((ext_vector_type(2))) long;

__device__ __constant__ int c_docmap[6] = {0, 1, 0, 2, 1, 2};

__device__ inline unsigned short f2bf(float f) {
    __hip_bfloat16 h = __float2bfloat16(f);
    return reinterpret_cast<unsigned short&>(h);
}
__device__ inline float bf2f(unsigned short u) {
    return __uint_as_float((unsigned int)u << 16);
}
__device__ inline unsigned char f2fp8(float f) {
    __hip_fp8_e4m3 t(f);           // OCP e4m3fn, RNE+sat
    return t.__x;
}

// ---------------- fused prep: doc conversion + weight transposes ----------------
__global__ void prep(const float* __restrict__ d0, const float* __restrict__ d1,
                     const float* __restrict__ d2, const float* __restrict__ W1s,
                     const float* __restrict__ W2s, unsigned short* __restrict__ Xb,
                     unsigned short* __restrict__ W1t, unsigned short* __restrict__ W2t) {
    int seg = blockIdx.y;
    size_t i4 = ((size_t)blockIdx.x * 256 + threadIdx.x) * 4;
    if (seg < 3) {
        const size_t n1 = (size_t)N_ROWS * IN_DIM;
        if (i4 >= n1) return;
        const float* src = (seg == 0) ? d0 : ((seg == 1) ? d1 : d2);
        float4 v = *(const float4*)(src + i4);
        ushort4 o;
        o.x = f2bf(v.x); o.y = f2bf(v.y); o.z = f2bf(v.z); o.w = f2bf(v.w);
        *(ushort4*)(Xb + seg * n1 + i4) = o;
    } else if (seg == 3) {
        const size_t tot = (size_t)6 * IN_DIM * OUT_DIM;
        if (i4 >= tot) return;
        size_t r = i4;
        int z = (int)(r / ((size_t)OUT_DIM * IN_DIM)); r %= (size_t)OUT_DIM * IN_DIM;
        int n = (int)(r / IN_DIM);
        int k = (int)(r % IN_DIM);
        const float* W = W1s + (size_t)z * IN_DIM * OUT_DIM;
        ushort4 o;
        o.x = f2bf(W[(size_t)(k + 0) * OUT_DIM + n]);
        o.y = f2bf(W[(size_t)(k + 1) * OUT_DIM + n]);
        o.z = f2bf(W[(size_t)(k + 2) * OUT_DIM + n]);
        o.w = f2bf(W[(size_t)(k + 3) * OUT_DIM + n]);
        *(ushort4*)(W1t + i4) = o;
    } else {
        const size_t tot = (size_t)6 * OUT_DIM * OUT_DIM;
        if (i4 >= tot) return;
        size_t r = i4;
        int z = (int)(r / ((size_t)OUT_DIM * OUT_DIM)); r %= (size_t)OUT_DIM * OUT_DIM;
        int n = (int)(r / OUT_DIM);
        int k = (int)(r % OUT_DIM);
        const float* W = W2s + (size_t)z * OUT_DIM * OUT_DIM;
        ushort4 o;
        o.x = f2bf(W[(size_t)(k + 0) * OUT_DIM + n]);
        o.y = f2bf(W[(size_t)(k + 1) * OUT_DIM + n]);
        o.z = f2bf(W[(size_t)(k + 2) * OUT_DIM + n]);
        o.w = f2bf(W[(size_t)(k + 3) * OUT_DIM + n]);
        *(ushort4*)(W2t + i4) = o;
    }
}

// ---------------- async swizzled staging (bf16, 128 rows x 64 cols) ----------------
__device__ inline void stage_tile_async(const unsigned short* __restrict__ G, int ld,
                                        int row0, int k0, unsigned short* lds,
                                        int wave, int lane) {
    int rbase = wave * 32;
#pragma unroll
    for (int i = 0; i < 4; ++i) {
        int rs = rbase + i * 8;
        int r  = rs + (lane >> 3);
        int pc = lane & 7;
        int lc = pc ^ (r & 7);
        const unsigned short* g = G + (size_t)(row0 + r) * ld + k0 + lc * 8;
        unsigned short* l = lds + rs * 64;
        __builtin_amdgcn_global_load_lds(
            (const __attribute__((address_space(1))) unsigned int*)g,
            (__attribute__((address_space(3))) unsigned int*)l, 16, 0, 0);
    }
}

__device__ inline void mfma_step_swz(const unsigned short* As, const unsigned short* Bs,
                                     int wrow, int wcol, int lane15, int quad,
                                     f32x4 acc[4][4]) {
#pragma unroll
    for (int kk = 0; kk < BK; kk += 32) {
        int lcb = (kk >> 3) + quad;
        bf16x8 aF[4], bF[4];
#pragma unroll
        for (int t = 0; t < 4; ++t) {
            int row = wrow + t * 16 + lane15;
            aF[t] = *(const bf16x8*)(As + row * 64 + ((lcb ^ (row & 7)) * 8));
        }
#pragma unroll
        for (int t = 0; t < 4; ++t) {
            int row = wcol + t * 16 + lane15;
            bF[t] = *(const bf16x8*)(Bs + row * 64 + ((lcb ^ (row & 7)) * 8));
        }
#pragma unroll
        for (int mt = 0; mt < 4; ++mt)
#pragma unroll
            for (int nt = 0; nt < 4; ++nt)
                acc[mt][nt] = __builtin_amdgcn_mfma_f32_16x16x32_bf16(aF[mt], bF[nt], acc[mt][nt], 0, 0, 0);
    }
}

// ---------------- GEMM1: X @ W1^T + b1, fused BN-stats, FP32 out ----------------
__global__ __launch_bounds__(256) void gemm1_bn(
    const unsigned short* __restrict__ Xb, const unsigned short* __restrict__ W1t,
    const float* __restrict__ biasAll, float* __restrict__ H,
    float* __restrict__ stats) {
    int z = blockIdx.z;
    const unsigned short* A = Xb + (size_t)c_docmap[z] * N_ROWS * IN_DIM;
    const unsigned short* B = W1t + (size_t)z * OUT_DIM * IN_DIM;
    const float* bz = biasAll + (size_t)z * OUT_DIM;
    float* C = H + (size_t)z * N_ROWS * OUT_DIM;

    int m0 = blockIdx.y * BM, n0 = blockIdx.x * BN;
    int tid = threadIdx.x;
    int wave = tid >> 6, lane = tid & 63;
    int lane15 = lane & 15, quad = lane >> 4;
    int wrow = (wave >> 1) * 64, wcol = (wave & 1) * 64;

    __shared__ unsigned short As[BM * 64];
    __shared__ unsigned short Bs[BN * 64];

    f32x4 acc[4][4];
#pragma unroll
    for (int mt = 0; mt < 4; ++mt)
#pragma unroll
        for (int nt = 0; nt < 4; ++nt)
            acc[mt][nt] = (f32x4){0.f, 0.f, 0.f, 0.f};

    for (int k0 = 0; k0 < IN_DIM; k0 += BK) {
        stage_tile_async(A, IN_DIM, m0, k0, As, wave, lane);
        stage_tile_async(B, IN_DIM, n0, k0, Bs, wave, lane);
        __syncthreads();
        mfma_step_swz(As, Bs, wrow, wcol, lane15, quad, acc);
        __syncthreads();
    }

    float s1[4] = {0.f, 0.f, 0.f, 0.f}, s2[4] = {0.f, 0.f, 0.f, 0.f};
#pragma unroll
    for (int nt = 0; nt < 4; ++nt) {
        int col = n0 + wcol + nt * 16 + lane15;
        float bv = bz[col];
#pragma unroll
        for (int mt = 0; mt < 4; ++mt)
#pragma unroll
            for (int r = 0; r < 4; ++r) {
                int row = m0 + wrow + mt * 16 + quad * 4 + r;
                float v = acc[mt][nt][r] + bv;
                C[(size_t)row * OUT_DIM + col] = v;
                s1[nt] += v; s2[nt] += v * v;
            }
    }
#pragma unroll
    for (int nt = 0; nt < 4; ++nt) {
        float a = s1[nt], b = s2[nt];
        a += __shfl_xor(a, 16); a += __shfl_xor(a, 32);
        b += __shfl_xor(b, 16); b += __shfl_xor(b, 32);
        if (quad == 0) {
            int col = n0 + wcol + nt * 16 + lane15;
            atomicAdd(&stats[((size_t)z * OUT_DIM + col) * 2 + 0], a);
            atomicAdd(&stats[((size_t)z * OUT_DIM + col) * 2 + 1], b);
        }
    }
}

// ---------------- BN apply + ReLU: fp32 H -> bf16 Hb ----------------
__global__ void bn_apply(const float* __restrict__ H, unsigned short* __restrict__ Hb,
                         const float* __restrict__ stats, const float* __restrict__ gammas,
                         const float* __restrict__ betas) {
    size_t i4 = ((size_t)blockIdx.x * blockDim.x + threadIdx.x) * 4;
    if (i4 >= (size_t)6 * N_ROWS * OUT_DIM) return;
    int c = (int)(i4 % OUT_DIM);
    int k = (int)(i4 / ((size_t)N_ROWS * OUT_DIM));
    float4 h = *(const float4*)(H + i4);
    float hv[4] = {h.x, h.y, h.z, h.w};
    ushort4 o;
    unsigned short* ov = (unsigned short*)&o;
#pragma unroll
    for (int j = 0; j < 4; ++j) {
        size_t sc = (size_t)k * OUT_DIM + c + j;
        float mu = stats[sc * 2 + 0] * (1.f / N_ROWS);
        float var = stats[sc * 2 + 1] * (1.f / N_ROWS) - mu * mu;
        float v = (hv[j] - mu) * rsqrtf(var + 1e-5f) * gammas[sc] + betas[sc];
        ov[j] = f2bf(fmaxf(v, 0.f));
    }
    *(ushort4*)(Hb + i4) = o;
}

// ---------------- GEMM2: Hb @ W2^T + b2, fused row-sumsq, BF16 out ----------------
__global__ __launch_bounds__(256) void gemm2_norm(
    const unsigned short* __restrict__ Hb, const unsigned short* __restrict__ W2t,
    const float* __restrict__ biasAll, unsigned short* __restrict__ O,
    float* __restrict__ rowsumsq) {
    int z = blockIdx.z;
    const unsigned short* A = Hb + (size_t)z * N_ROWS * OUT_DIM;
    const unsigned short* B = W2t + (size_t)z * OUT_DIM * OUT_DIM;
    const float* bz = biasAll + (size_t)z * OUT_DIM;
    unsigned short* C = O + (size_t)z * N_ROWS * OUT_DIM;
    float* rq = rowsumsq + (size_t)z * N_ROWS;

    int m0 = blockIdx.y * BM, n0 = blockIdx.x * BN;
    int tid = threadIdx.x;
    int wave = tid >> 6, lane = tid & 63;
    int lane15 = lane & 15, quad = lane >> 4;
    int wrow = (wave >> 1) * 64, wcol = (wave & 1) * 64;

    __shared__ unsigned short As[BM * 64];
    __shared__ unsigned short Bs[BN * 64];

    f32x4 acc[4][4];
#pragma unroll
    for (int mt = 0; mt < 4; ++mt)
#pragma unroll
        for (int nt = 0; nt < 4; ++nt)
            acc[mt][nt] = (f32x4){0.f, 0.f, 0.f, 0.f};

    for (int k0 = 0; k0 < OUT_DIM; k0 += BK) {
        stage_tile_async(A, OUT_DIM, m0, k0, As, wave, lane);
        stage_tile_async(B, OUT_DIM, n0, k0, Bs, wave, lane);
        __syncthreads();
        mfma_step_swz(As, Bs, wrow, wcol, lane15, quad, acc);
        __syncthreads();
    }

    float rs[16];
#pragma unroll
    for (int j = 0; j < 16; ++j) rs[j] = 0.f;
#pragma unroll
    for (int nt = 0; nt < 4; ++nt) {
        int col = n0 + wcol + nt * 16 + lane15;
        float bv = bz[col];
#pragma unroll
        for (int mt = 0; mt < 4; ++mt)
#pragma unroll
            for (int r = 0; r < 4; ++r) {
                int row = m0 + wrow + mt * 16 + quad * 4 + r;
                float v = acc[mt][nt][r] + bv;
                C[(size_t)row * OUT_DIM + col] = f2bf(v);
                rs[mt * 4 + r] += v * v;
            }
    }
#pragma unroll
    for (int j = 0; j < 16; ++j) {
        float v = rs[j];
        v += __shfl_xor(v, 1); v += __shfl_xor(v, 2);
        v += __shfl_xor(v, 4); v += __shfl_xor(v, 8);
        if (lane15 == 0) {
            int row = m0 + wrow + (j >> 2) * 16 + quad * 4 + (j & 3);
            atomicAdd(&rq[row], v);
        }
    }
}

// ---------------- row L2 norm: bf16 O -> fp8 e4m3, K-PERMUTED layout ----------------
// Within each 128-byte block of a row: logical k = t*32 + q*8 + j stored at
// phys = q*32 + t*8 + j (t,q in 0..3). Gram dots are K-permutation invariant.
__global__ __launch_bounds__(256) void l2norm_fp8(const unsigned short* __restrict__ O,
                                                  const float* __restrict__ rowsumsq,
                                                  unsigned char* __restrict__ A) {
    int wave = threadIdx.x >> 6, lane = threadIdx.x & 63;
    int row = blockIdx.x * 4 + wave;
    float sc = 1.f / fmaxf(sqrtf(rowsumsq[row]), 1e-12f);
    const unsigned short* Op = O + (size_t)row * OUT_DIM + lane * 8;
    uint4 u = *(const uint4*)Op;
    unsigned int w[4] = {u.x, u.y, u.z, u.w};
    unsigned long long pk = 0;
#pragma unroll
    for (int j = 0; j < 8; ++j) {
        unsigned short us = (j & 1) ? (unsigned short)(w[j >> 1] >> 16)
                                    : (unsigned short)(w[j >> 1] & 0xffff);
        pk |= (unsigned long long)f2fp8(bf2f(us) * sc) << (8 * j);
    }
    // permuted physical position for this lane's 8 logical bytes
    int phys = ((lane >> 4) << 7) + ((lane & 3) << 5) + (((lane >> 2) & 3) << 3);
    *(unsigned long long*)(A + (size_t)row * OUT_DIM + phys) = pk;
}

// ---------------- fp8 staging: 128 rows x 128 byte-cols, swizzled ----------------
__device__ inline void stage_fp8(const unsigned char* __restrict__ G, int ld,
                                 int row0, int k0, unsigned char* lds,
                                 int wave, int lane) {
    int rbase = wave * 32;
#pragma unroll
    for (int i = 0; i < 4; ++i) {
        int rs = rbase + i * 8;
        int r  = rs + (lane >> 3);
        int pc = lane & 7;
        int lc = pc ^ (r & 7);
        const unsigned char* g = G + (size_t)(row0 + r) * ld + k0 + lc * 16;
        unsigned char* l = lds + rs * 128;
        __builtin_amdgcn_global_load_lds(
            (const __attribute__((address_space(1))) unsigned int*)g,
            (__attribute__((address_space(3))) unsigned int*)l, 16, 0, 0);
    }
}

// ---------------- symmetric fp8 Gram: b128 reads, double-buffered ----------------
// Cm = [o1;o2]: [8192][512] fp8 e4m3 (K-permuted), rows L2-normalized.
// 128x128 tiles, I<=J: 2080 blocks/pair. BK=128B, 4 k-steps, dbuf LDS (64 KB).
// Read: lane (quad q) ds_read_b128 at chunk (2q+t2)^(row&7) -> frags for
// kk = 2*t2 (low 8B) and 2*t2+1 (high 8B). Bank-balanced: 32 banks x 8 each.
__global__ __launch_bounds__(256) void gram_kernel(const unsigned char* __restrict__ Abase,
                                                   float* __restrict__ rowsum,
                                                   float* __restrict__ selfdot,
                                                   float* __restrict__ crossdot) {
    int p = blockIdx.z;
    const unsigned char* Cm = Abase + (size_t)p * 2 * N_ROWS * OUT_DIM;

    int idx = blockIdx.x, I = 0;
    while (idx >= 64 - I) { idx -= 64 - I; ++I; }
    int J = I + idx;
    int m0 = I * BM, n0 = J * BM;
    bool isDiag  = (I == J);
    bool isCross = (J == I + N_ROWS / BM);

    int tid = threadIdx.x;
    int wave = tid >> 6, lane = tid & 63;
    int lane15 = lane & 15, quad = lane >> 4;
    int wrow = (wave >> 1) * 64, wcol = (wave & 1) * 64;

    __shared__ unsigned char As[2][BM * 128];   // 2 x 16 KB
    __shared__ unsigned char Bs[2][BM * 128];   // 2 x 16 KB

    f32x4 acc[4][4];
#pragma unroll
    for (int mt = 0; mt < 4; ++mt)
#pragma unroll
        for (int nt = 0; nt < 4; ++nt)
            acc[mt][nt] = (f32x4){0.f, 0.f, 0.f, 0.f};

    stage_fp8(Cm, OUT_DIM, m0, 0, As[0], wave, lane);
    if (!isDiag) stage_fp8(Cm, OUT_DIM, n0, 0, Bs[0], wave, lane);
    __syncthreads();

#pragma unroll
    for (int i = 0; i < 4; ++i) {
        int cur = i & 1;
        if (i < 3) {
            stage_fp8(Cm, OUT_DIM, m0, (i + 1) * 128, As[cur ^ 1], wave, lane);
            if (!isDiag) stage_fp8(Cm, OUT_DIM, n0, (i + 1) * 128, Bs[cur ^ 1], wave, lane);
        }
        const unsigned char* Ap = As[cur];
        const unsigned char* Bp = isDiag ? As[cur] : Bs[cur];
#pragma unroll
        for (int t2 = 0; t2 < 2; ++t2) {
            int c16 = 2 * quad + t2;
            i64x2 aF[4], bF[4];
#pragma unroll
            for (int t = 0; t < 4; ++t) {
                int row = wrow + t * 16 + lane15;
                aF[t] = *(const i64x2*)(Ap + row * 128 + ((c16 ^ (row & 7)) << 4));
            }
#pragma unroll
            for (int t = 0; t < 4; ++t) {
                int row = wcol + t * 16 + lane15;
                bF[t] = *(const i64x2*)(Bp + row * 128 + ((c16 ^ (row & 7)) << 4));
            }
#pragma unroll
            for (int half = 0; half < 2; ++half)
#pragma unroll
                for (int mt = 0; mt < 4; ++mt)
#pragma unroll
                    for (int nt = 0; nt < 4; ++nt)
                        acc[mt][nt] = __builtin_amdgcn_mfma_f32_16x16x32_fp8_fp8(
                            aF[mt][half], bF[nt][half], acc[mt][nt], 0, 0, 0);
        }
        __syncthreads();
    }

    float* sdp = selfdot + (size_t)p * 2 * N_ROWS;
    float* cdp = crossdot + (size_t)p * 2 * N_ROWS;
    float* rp  = rowsum  + (size_t)p * 2 * N_ROWS;

    float rs[16];
    float cs[4];
#pragma unroll
    for (int j = 0; j < 16; ++j) rs[j] = 0.f;
#pragma unroll
    for (int j = 0; j < 4; ++j) cs[j] = 0.f;

#pragma unroll
    for (int mt = 0; mt < 4; ++mt)
#pragma unroll
        for (int nt = 0; nt < 4; ++nt) {
            int gcol = n0 + wcol + nt * 16 + lane15;
#pragma unroll
            for (int r = 0; r < 4; ++r) {
                int grow = m0 + wrow + mt * 16 + quad * 4 + r;
                float s = acc[mt][nt][r];
                float e = __expf(2.f * s);
                rs[mt * 4 + r] += e;
                cs[nt] += e;
                if (isDiag && gcol == grow) sdp[grow] = s;
                if (isCross && gcol == grow + N_ROWS) { cdp[grow] = s; cdp[gcol] = s; }
            }
        }

#pragma unroll
    for (int j = 0; j < 16; ++j) {
        float v = rs[j];
        v += __shfl_xor(v, 1); v += __shfl_xor(v, 2);
        v += __shfl_xor(v, 4); v += __shfl_xor(v, 8);
        rs[j] = v;
    }
    if (lane15 == 0) {
#pragma unroll
        for (int j = 0; j < 16; ++j) {
            int grow = m0 + wrow + (j >> 2) * 16 + quad * 4 + (j & 3);
            atomicAdd(&rp[grow], rs[j]);
        }
    }

    if (!isDiag) {
#pragma unroll
        for (int n = 0; n < 4; ++n) {
            float v = cs[n];
            v += __shfl_xor(v, 16); v += __shfl_xor(v, 32);
            cs[n] = v;
        }
        if (quad == 0) {
#pragma unroll
            for (int n = 0; n < 4; ++n) {
                int gcol = n0 + wcol + n * 16 + lane15;
                atomicAdd(&rp[gcol], cs[n]);
            }
        }
    }
}

// ---------------- final loss reduction ----------------
__global__ void loss_kernel(const float* __restrict__ rowsum, const float* __restrict__ selfdot,
                            const float* __restrict__ crossdot, float* __restrict__ out) {
    __shared__ float red[256];
    float acc = 0.f;
    for (int i = threadIdx.x; i < 3 * 2 * N_ROWS; i += 256) {
        float denom = rowsum[i] - __expf(2.f * selfdot[i]);
        acc += logf(denom) - 2.f * crossdot[i];
    }
    red[threadIdx.x] = acc;
    __syncthreads();
    for (int s = 128; s > 0; s >>= 1) {
        if (threadIdx.x < s) red[threadIdx.x] += red[threadIdx.x + s];
        __syncthreads();
    }
    if (threadIdx.x == 0) out[0] = red[0] * (1.f / 24576.f);
}

// ---------------- launch ----------------
extern "C" void kernel_launch(void* const* d_in, const int* in_sizes, int n_in,
                              void* d_out, int out_size, void* d_ws, size_t ws_size,
                              hipStream_t stream) {
    const float* doc0   = (const float*)d_in[0];
    const float* doc1   = (const float*)d_in[1];
    const float* doc2   = (const float*)d_in[2];
    const float* W1s    = (const float*)d_in[3];
    const float* b1s    = (const float*)d_in[4];
    const float* gammas = (const float*)d_in[5];
    const float* betas  = (const float*)d_in[6];
    const float* W2s    = (const float*)d_in[7];
    const float* b2s    = (const float*)d_in[8];
    float* out = (float*)d_out;

    char* base = (char*)d_ws;
    size_t off = 0;
    auto alloc = [&](size_t bytes) -> char* {
        char* r = base + off;
        off += (bytes + 255) & ~(size_t)255;
        return r;
    };

    // Xb (18.9 MB) dead after gemm1 -> Abuf (12.6 MB) aliases it.
    // H fp32 (50.3 MB) dead after bn_apply -> O bf16 (25.2 MB) aliases it.
    unsigned short* Xb   = (unsigned short*)alloc((size_t)3 * N_ROWS * IN_DIM * 2);
    unsigned short* W1t  = (unsigned short*)alloc((size_t)6 * OUT_DIM * IN_DIM * 2);
    unsigned short* W2t  = (unsigned short*)alloc((size_t)6 * OUT_DIM * OUT_DIM * 2);
    float*          H    = (float*)         alloc((size_t)6 * N_ROWS * OUT_DIM * 4);
    unsigned short* Hb   = (unsigned short*)alloc((size_t)6 * N_ROWS * OUT_DIM * 2);
    unsigned char*  Abuf = (unsigned char*)Xb;
    unsigned short* O    = (unsigned short*)H;
    // zero-init region (one memset): stats + rowsumsq + rowsum
    char* zbase = alloc(24576 + 98304 + 98304);
    float* stats    = (float*)zbase;
    float* rowsumsq = (float*)(zbase + 24576);
    float* rowsum   = (float*)(zbase + 24576 + 98304);
    float* sdot     = (float*)alloc((size_t)3 * 2 * N_ROWS * 4);
    float* cdot     = (float*)alloc((size_t)3 * 2 * N_ROWS * 4);

    if (ws_size < off) return;

    hipMemsetAsync(zbase, 0, 24576 + 98304 + 98304, stream);

    prep<<<dim3(3072, 5), 256, 0, stream>>>(doc0, doc1, doc2, W1s, W2s, Xb, W1t, W2t);

    gemm1_bn<<<dim3(OUT_DIM / BN, N_ROWS / BM, 6), 256, 0, stream>>>(Xb, W1t, b1s, H, stats);

    bn_apply<<<(int)(((size_t)6 * N_ROWS * OUT_DIM / 4 + 255) / 256), 256, 0, stream>>>(
        H, Hb, stats, gammas, betas);

    gemm2_norm<<<dim3(OUT_DIM / BN, N_ROWS / BM, 6), 256, 0, stream>>>(Hb, W2t, b2s, O, rowsumsq);

    l2norm_fp8<<<6 * N_ROWS / 4, 256, 0, stream>>>(O, rowsumsq, Abuf);

    // symmetric fp8 gram: 64*65/2 = 2080 tile-pairs per pair, 3 pairs
    gram_kernel<<<dim3(2080, 1, 3), 256, 0, stream>>>(Abuf, rowsum, sdot, cdot);

    loss_kernel<<<1, 256, 0, stream>>>(rowsum, sdot, cdot, out);
}